// Round 3
// baseline (14342.882 us; speedup 1.0000x reference)
//
#include <hip/hip_runtime.h>
#include <cmath>

// TimeLSTMCell B=64, S=512, E=256, H=512 fp32.
// Persistent kernel, 256 WGs x 1024 thr (1 WG/CU, 16 waves = 4/SIMD).
// WG (bg,cg): bg in [0,4) -> 16 batches, cg in [0,64) -> 8 hidden cols.
// bg-groups are independent -> 4 separate 64-WG barriers.
// Thread (jl = t>>7 col, bq = (t>>5)&3 batch-quad, kq = t&31 K-slice):
//   phase A: 4 gates x 4 batches, K=768 split 32 ways (x-part prefetched into
//            the previous step's barrier-wait window);
//   phase B: 1 col x 4 batches, K=512 split 32 ways.
// Reductions: waves 0-7 reduce gates, waves 8-9 reduce d + tanh, wave 10 decay;
// then 512-thread activation phase (wave-uniform gate), 128-thread finale.
// Cross-WG h/c via relaxed AGENT-scope (sc1) loads/stores - no cache-wide
// fences, weights stay hot in L1/L2 all 512 steps. __syncthreads drains
// vmcnt(0) per wave before s_barrier => sc1 stores visible before flag store.

#define Bdim 64
#define Sdim 512
#define Edim 256
#define Hdim 512
#define NWG  256
#define NT   1024
#define FSTR 16   // flag padding (ints): 64B per flag line

__device__ __forceinline__ float ld_dev(const float* p) {
    return __hip_atomic_load(p, __ATOMIC_RELAXED, __HIP_MEMORY_SCOPE_AGENT);
}
__device__ __forceinline__ void st_dev(float* p, float v) {
    __hip_atomic_store(p, v, __ATOMIC_RELAXED, __HIP_MEMORY_SCOPE_AGENT);
}
__device__ __forceinline__ float dot4(float4 a, float4 b) {
    return a.x*b.x + a.y*b.y + a.z*b.z + a.w*b.w;
}

__global__ __launch_bounds__(NT, 4) void tlstm(
    const float* __restrict__ x,       // [B,S,E]
    const float* __restrict__ ts,      // [B,S]
    const float* __restrict__ Wall,    // [4H,H]
    const float* __restrict__ Wall_b,  // [4H]
    const float* __restrict__ Uall,    // [4H,E]
    const float* __restrict__ Uall_b,  // [4H]
    const float* __restrict__ Wd,      // [H,H]
    const float* __restrict__ Wd_b,    // [H]
    float* __restrict__ out,           // [B,S,H] | h_f[B,H] | c_f[B,H]
    float* __restrict__ ws)            // flags[256*FSTR] | cb0[B*H] | cb1[B*H]
{
    __shared__ float h_s[16 * 512];     // 32 KB
    __shared__ float c_s[16 * 512];     // 32 KB
    __shared__ float redA[512 * 33];    // 67.6 KB
    __shared__ float redB[128 * 33];    // 16.9 KB
    __shared__ float gv[4 * 136];       // gate pre-activations, wave-uniform-g layout
    __shared__ float act[4 * 136];
    __shared__ float cs1v[128];
    __shared__ float decv[16];

    int*   flags = (int*)ws;
    float* cb0   = ws + NWG * FSTR;
    float* cb1   = cb0 + Bdim * Hdim;
    float* cb[2] = {cb0, cb1};

    const int t   = threadIdx.x;
    const int bg  = blockIdx.x >> 6;   // 0..3
    const int cg  = blockIdx.x & 63;   // 0..63
    const int b0  = bg * 16;
    const int j0  = cg * 8;
    const int jl  = t >> 7;            // 0..7: col within WG
    const int sub = t & 127;
    const int bq  = sub >> 5;          // 0..3: batch quad
    const int kq  = sub & 31;          // 0..31: K slice
    const int jw  = j0 + jl;           // this thread's weight column

    // Step-invariant weight row pointers (plain cached loads; L1/L2-hot).
    const float4* wr0 = (const float4*)(Wall + (size_t)(0 * Hdim + jw) * Hdim);
    const float4* wr1 = (const float4*)(Wall + (size_t)(1 * Hdim + jw) * Hdim);
    const float4* wr2 = (const float4*)(Wall + (size_t)(2 * Hdim + jw) * Hdim);
    const float4* wr3 = (const float4*)(Wall + (size_t)(3 * Hdim + jw) * Hdim);
    const float4* ur0 = (const float4*)(Uall + (size_t)(0 * Hdim + jw) * Edim);
    const float4* ur1 = (const float4*)(Uall + (size_t)(1 * Hdim + jw) * Edim);
    const float4* ur2 = (const float4*)(Uall + (size_t)(2 * Hdim + jw) * Edim);
    const float4* ur3 = (const float4*)(Uall + (size_t)(3 * Hdim + jw) * Edim);
    const float4* dr  = (const float4*)(Wd + (size_t)jw * Hdim);

    const float* xb = x + (size_t)(b0 + bq * 4) * Sdim * Edim;

    float xacc[4][4];
    // x-part of gate dots for step `s` (no recurrent dependence).
    auto xpart = [&](int s) {
        #pragma unroll
        for (int g = 0; g < 4; ++g)
            #pragma unroll
            for (int i = 0; i < 4; ++i) xacc[g][i] = 0.0f;
        #pragma unroll
        for (int cc = 0; cc < 2; ++cc) {
            const int f4i = cc * 32 + kq;          // 0..63
            float4 u0 = ur0[f4i], u1 = ur1[f4i], u2 = ur2[f4i], u3 = ur3[f4i];
            #pragma unroll
            for (int i = 0; i < 4; ++i) {
                float4 xv = ((const float4*)(xb + (size_t)i * Sdim * Edim
                                               + (size_t)s * Edim))[f4i];
                xacc[0][i] += dot4(xv, u0);
                xacc[1][i] += dot4(xv, u1);
                xacc[2][i] += dot4(xv, u2);
                xacc[3][i] += dot4(xv, u3);
            }
        }
    };

    xpart(0);  // prologue: step-0 x partials

    for (int s = 0; s < Sdim; ++s) {
        // ---- stage h, c into LDS ----
        if (s == 0) {
            #pragma unroll
            for (int p = 0; p < 8; ++p) {
                h_s[p * 1024 + t] = 0.0f;
                c_s[p * 1024 + t] = 0.0f;
            }
        } else {
            const float* csrc = cb[s & 1] + b0 * Hdim;
            #pragma unroll
            for (int p = 0; p < 8; ++p) {
                const int idx = p * 1024 + t;
                const int row = idx >> 9;
                const int col = idx & 511;
                h_s[idx] = ld_dev(out + (size_t)(b0 + row) * Sdim * Hdim
                                      + (size_t)(s - 1) * Hdim + col);
                c_s[idx] = ld_dev(csrc + row * Hdim + col);
            }
        }
        __syncthreads();

        // ---- phase A: gate partials (4 gates x 4 batches), init from x-part ----
        float acc[4][4];
        #pragma unroll
        for (int g = 0; g < 4; ++g)
            #pragma unroll
            for (int i = 0; i < 4; ++i) acc[g][i] = xacc[g][i];

        #pragma unroll
        for (int cc = 0; cc < 4; ++cc) {
            const int f4i = cc * 32 + kq;          // 0..127
            float4 w0 = wr0[f4i], w1 = wr1[f4i], w2 = wr2[f4i], w3 = wr3[f4i];
            #pragma unroll
            for (int i = 0; i < 4; ++i) {
                float4 hv = *(const float4*)(h_s + (bq * 4 + i) * 512 + f4i * 4);
                acc[0][i] += dot4(hv, w0);
                acc[1][i] += dot4(hv, w1);
                acc[2][i] += dot4(hv, w2);
                acc[3][i] += dot4(hv, w3);
            }
        }

        // ---- phase B: c_s1 partials (1 col x 4 batches) ----
        float accB[4] = {0.f, 0.f, 0.f, 0.f};
        #pragma unroll
        for (int cc = 0; cc < 4; ++cc) {
            const int f4i = cc * 32 + kq;
            float4 dv = dr[f4i];
            #pragma unroll
            for (int i = 0; i < 4; ++i) {
                float4 cv = *(const float4*)(c_s + (bq * 4 + i) * 512 + f4i * 4);
                accB[i] += dot4(cv, dv);
            }
        }

        // ---- write partials (stride-33: conflict-free) ----
        #pragma unroll
        for (int g = 0; g < 4; ++g)
            #pragma unroll
            for (int i = 0; i < 4; ++i)
                redA[((jl * 4 + g) * 16 + bq * 4 + i) * 33 + kq] = acc[g][i];
        #pragma unroll
        for (int i = 0; i < 4; ++i)
            redB[(jl * 16 + bq * 4 + i) * 33 + kq] = accB[i];
        __syncthreads();

        // ---- parallel reductions ----
        if (t < 512) {                       // waves 0-7: gate sums + biases
            float sum = 0.0f;
            #pragma unroll
            for (int k = 0; k < 32; ++k) sum += redA[t * 33 + k];
            const int g  = (t >> 4) & 3;
            const int jj = t >> 6;
            const int bl = t & 15;
            const int jc = j0 + jj;
            gv[g * 136 + jj * 16 + bl] =
                sum + Wall_b[g * Hdim + jc] + Uall_b[g * Hdim + jc];
        } else if (t < 640) {                // waves 8-9: d sums + tanh
            const int u = t - 512;           // u = jl*16 + bl
            float sum = 0.0f;
            #pragma unroll
            for (int k = 0; k < 32; ++k) sum += redB[u * 33 + k];
            cs1v[u] = tanhf(sum + Wd_b[j0 + (u >> 4)]);
        } else if (t < 656) {                // wave 10 (16 lanes): decay
            const int bl = t - 640;
            decv[bl] = 1.0f / logf(2.7182818284590452f
                                   + ts[(b0 + bl) * Sdim + s]);
        }
        __syncthreads();

        // ---- activations: 512 threads, gate uniform per wave ----
        if (t < 512) {
            const int g  = t >> 7;
            const int id = t & 127;
            const float v = gv[g * 136 + id];
            act[g * 136 + id] = (g == 3) ? tanhf(v)
                                         : 1.0f / (1.0f + expf(-v));
        }
        __syncthreads();

        // ---- finale: 128 threads (one per (col,batch)) ----
        if (t < 128) {
            const int jc = j0 + (t >> 4);
            const int bl = t & 15;
            const int b  = b0 + bl;
            const float cs1  = cs1v[t];
            const float dec  = decv[bl];
            const float cp   = c_s[bl * 512 + jc];
            const float cadj = (cp - cs1) + cs1 * dec;
            const float f  = act[0 * 136 + t];
            const float ii = act[1 * 136 + t];
            const float oo = act[2 * 136 + t];
            const float gg = act[3 * 136 + t];
            const float cn = f * cadj + ii * gg;
            const float hn = oo * tanhf(cn);
            st_dev(cb[(s + 1) & 1] + (size_t)b * Hdim + jc, cn);
            st_dev(out + ((size_t)b * Sdim + s) * Hdim + jc, hn);
            if (s == Sdim - 1) {
                float* hf = out + (size_t)Bdim * Sdim * Hdim;
                float* cf = hf + Bdim * Hdim;
                hf[b * Hdim + jc] = hn;
                cf[b * Hdim + jc] = cn;
            }
        }

        if (s == Sdim - 1) break;            // no barrier after last step

        __syncthreads();                     // drain finale's sc1 stores
        if (t == 0) {
            __hip_atomic_store(&flags[blockIdx.x * FSTR], s + 1,
                               __ATOMIC_RELAXED, __HIP_MEMORY_SCOPE_AGENT);
        }
        xpart(s + 1);                        // overlap with other WGs finishing
        if (t < 64) {                        // 64-WG group barrier (same bg only)
            while (__hip_atomic_load(&flags[(bg * 64 + t) * FSTR],
                                     __ATOMIC_RELAXED,
                                     __HIP_MEMORY_SCOPE_AGENT) < s + 1) {
                __builtin_amdgcn_s_sleep(1);
            }
        }
        __syncthreads();
    }
}

extern "C" void kernel_launch(void* const* d_in, const int* in_sizes, int n_in,
                              void* d_out, int out_size, void* d_ws, size_t ws_size,
                              hipStream_t stream) {
    const float* x      = (const float*)d_in[0];
    const float* ts     = (const float*)d_in[1];
    const float* Wall   = (const float*)d_in[2];
    const float* Wall_b = (const float*)d_in[3];
    const float* Uall   = (const float*)d_in[4];
    const float* Uall_b = (const float*)d_in[5];
    const float* Wd     = (const float*)d_in[6];
    const float* Wd_b   = (const float*)d_in[7];

    tlstm<<<NWG, NT, 0, stream>>>(x, ts, Wall, Wall_b, Uall, Uall_b, Wd, Wd_b,
                                  (float*)d_out, (float*)d_ws);
}

// Round 4
// 3090.174 us; speedup vs baseline: 4.6414x; 4.6414x over previous
//
#include <hip/hip_runtime.h>
#include <cmath>

// TimeLSTMCell B=64, S=512, E=256, H=512.
// Round 4: bf16 MFMA (16x16x32) with WEIGHTS HELD IN REGISTERS as pre-packed
// B-fragments (32 VGPRs/lane), persistent 256-WG kernel, 1 grid barrier/step.
//
// Pre-pass kernel packs fp32 weights -> bf16 MFMA B-fragments in d_ws and
// zeroes the h/c bf16 mirrors + flags. Main kernel: WG(bg,cg) owns 16 batches
// x 8 hidden cols (= 32 gate-cols = 2 MFMA B-tiles of 16), NT=512 (8 waves).
// Waves 0-3: gate tile0 K-slices, waves 4-7: tile1; all waves: 2 d-MFMAs.
// A-fragments (h/x/c, bf16) staged in LDS; C partials reduced via LDS.
// Cross-WG state: bf16 h/c mirrors in ws, double-buffered, accessed with
// relaxed AGENT-scope atomics (coherent at LIC, no cache-wide fences ->
// everything else stays hot in L1/L2). `out` is write-only plain stores
// (flushed at kernel end). Per-bg 64-WG barrier, padded flags.
//
// MFMA 16x16x32 bf16 layouts (m89/m91/m120 verified):
//   A: m=lane&15, k=(lane>>4)*8+j   B: n=lane&15, k=(lane>>4)*8+j
//   D: n=lane&15, m=(lane>>4)*4+reg
// fp32 is kept for: biases, c carry (c_own), pointwise math. bf16 only enters
// GEMM operands -> expected absmax ~1e-2 vs threshold 2.98e-2.

typedef short bf16x8 __attribute__((ext_vector_type(8)));
typedef float f32x4  __attribute__((ext_vector_type(4)));

#define Bdim 64
#define Sdim 512
#define Edim 256
#define Hdim 512
#define NWG  256
#define NT   512
#define FSTR 16

// ws layout (bytes). Total ~4.3 MB.
#define WS_FLAGS 0
#define WS_HMIR0 16384
#define WS_HMIR1 (WS_HMIR0 + 65536)
#define WS_CMIR0 (WS_HMIR1 + 65536)
#define WS_CMIR1 (WS_CMIR0 + 65536)
#define WS_WFRAG (WS_CMIR1 + 65536)       // 64cg*2tile*24k*64lane*8 bf16 = 3 MB
#define WS_DFRAG (WS_WFRAG + 3145728)     // 64cg*16k*64lane*8 bf16 = 1 MB

__device__ __forceinline__ unsigned ld_dev_u32(const unsigned* p) {
    return __hip_atomic_load(p, __ATOMIC_RELAXED, __HIP_MEMORY_SCOPE_AGENT);
}
__device__ __forceinline__ void st_dev_u32(unsigned* p, unsigned v) {
    __hip_atomic_store(p, v, __ATOMIC_RELAXED, __HIP_MEMORY_SCOPE_AGENT);
}
__device__ __forceinline__ unsigned short f2bf(float f) {
    union { float f; unsigned u; } v; v.f = f;
    return (unsigned short)((v.u + 0x7FFFu + ((v.u >> 16) & 1u)) >> 16);  // RNE
}
__device__ __forceinline__ unsigned pack2(float lo, float hi) {
    return (unsigned)f2bf(lo) | ((unsigned)f2bf(hi) << 16);
}

// ---------------- pre-pass: pack weights, zero mirrors/flags ----------------
__global__ __launch_bounds__(256) void tlstm_prep(
    const float* __restrict__ Wall, const float* __restrict__ Uall,
    const float* __restrict__ Wd, unsigned char* __restrict__ ws)
{
    const int w = blockIdx.x, t = threadIdx.x;
    unsigned short* Wfrag = (unsigned short*)(ws + WS_WFRAG);
    unsigned short* Dfrag = (unsigned short*)(ws + WS_DFRAG);
    const int l = t & 63, ks = t >> 6, nn = l & 15, q = l >> 4;

    if (w < 128) {                       // gate fragments: WG = (cg, tile)
        const int cg = w >> 1, tile = w & 1;
        const int g = tile * 2 + (nn >> 3), jj = nn & 7;
        const int row = g * Hdim + cg * 8 + jj;
        for (int i = 0; i < 6; ++i) {
            const int kp = ks * 6 + i;   // 0..23
            const float* src = (kp < 16)
                ? Wall + (size_t)row * Hdim + kp * 32 + q * 8
                : Uall + (size_t)row * Edim + (kp - 16) * 32 + q * 8;
            unsigned* dst = (unsigned*)(Wfrag
                + (((size_t)(cg * 2 + tile) * 24 + kp) * 64 + l) * 8);
            #pragma unroll
            for (int p = 0; p < 4; ++p) dst[p] = pack2(src[2*p], src[2*p+1]);
        }
    } else if (w < 192) {                // d fragments: WG = cg
        const int cg = w - 128;
        int row = cg * 8 + nn; if (row > 511) row = 511;  // clamp (cols 8..15 unused)
        for (int i = 0; i < 4; ++i) {
            const int kp = ks * 4 + i;   // 0..15
            const float* src = Wd + (size_t)row * Hdim + kp * 32 + q * 8;
            unsigned* dst = (unsigned*)(Dfrag + (((size_t)cg * 16 + kp) * 64 + l) * 8);
            #pragma unroll
            for (int p = 0; p < 4; ++p) dst[p] = pack2(src[2*p], src[2*p+1]);
        }
    } else {                             // zero flags + all 4 mirrors (278528 B)
        const int idx = (w - 192) * 256 + t;          // 0..16383
        uint4* z = (uint4*)ws;
        for (int i = idx; i < 17408; i += 16384) z[i] = make_uint4(0, 0, 0, 0);
    }
}

// ------------------------------- main kernel --------------------------------
__global__ __launch_bounds__(NT, 2) void tlstm_mfma(
    const float* __restrict__ x,       // [B,S,E] fp32
    const float* __restrict__ ts,      // [B,S]
    const float* __restrict__ Wall_b,  // [4H]
    const float* __restrict__ Uall_b,  // [4H]
    const float* __restrict__ Wd_b,    // [H]
    float* __restrict__ out,           // [B,S,H] | h_f | c_f (write-only)
    unsigned char* __restrict__ ws)
{
    __shared__ unsigned short h_sb[16 * 520];   // bf16, row pad +8
    __shared__ unsigned short c_sb[16 * 520];
    __shared__ unsigned short x_sb[16 * 264];
    __shared__ float Cred[2][4][256];
    __shared__ float Dred[8][256];
    __shared__ float act[4 * 128];
    __shared__ float cs1v[128];
    __shared__ float c_own[128];                // fp32 c carry for own cols
    __shared__ float decv[16];

    int* flags = (int*)(ws + WS_FLAGS);
    const unsigned short* Wfrag = (const unsigned short*)(ws + WS_WFRAG);
    const unsigned short* Dfrag = (const unsigned short*)(ws + WS_DFRAG);

    const int t    = threadIdx.x;
    const int bg   = blockIdx.x >> 6, cg = blockIdx.x & 63;
    const int b0   = bg * 16, j0 = cg * 8;
    const int w    = t >> 6, lane = t & 63, q = lane >> 4, nn = lane & 15;
    const int tile = w >> 2, kbase = (w & 3) * 6;

    // ---- weights -> registers, once (32 VGPRs; L2-hot loads) ----
    bf16x8 bw[6];
    #pragma unroll
    for (int i = 0; i < 6; ++i)
        bw[i] = *(const bf16x8*)(Wfrag
            + (((size_t)(cg * 2 + tile) * 24 + kbase + i) * 64 + lane) * 8);
    bf16x8 bd[2];
    #pragma unroll
    for (int i = 0; i < 2; ++i)
        bd[i] = *(const bf16x8*)(Dfrag + (((size_t)cg * 16 + w * 2 + i) * 64 + lane) * 8);

    const int srow = t >> 5, scp = (t & 31) * 8;   // staging role: row 0..15, dword pos

    // stage x[b0..b0+16, sx, :] -> x_sb (plain cached loads, fp32 -> bf16)
    auto stage_x = [&](int sx) {
        const float4* xp = (const float4*)(x + ((size_t)(b0 + srow) * Sdim + sx) * Edim + scp);
        float4 v0 = xp[0], v1 = xp[1];
        unsigned* xd = (unsigned*)x_sb + srow * 132 + (scp >> 1);
        xd[0] = pack2(v0.x, v0.y); xd[1] = pack2(v0.z, v0.w);
        xd[2] = pack2(v1.x, v1.y); xd[3] = pack2(v1.z, v1.w);
    };

    if (t < 128) c_own[t] = 0.0f;
    stage_x(0);
    // mirrors buf0 zeroed by prep kernel (kernel-boundary ordering) -> no init barrier

    for (int s = 0; s < Sdim; ++s) {
        // ---- stage h, c (bf16 mirrors, LIC-coherent loads) ----
        {
            const unsigned* hsrc = (const unsigned*)(ws + WS_HMIR0 + (s & 1) * 65536);
            const unsigned* csrc = (const unsigned*)(ws + WS_CMIR0 + (s & 1) * 65536);
            const int goff = (b0 + srow) * 256 + scp;
            unsigned hv[8], cv[8];
            #pragma unroll
            for (int i = 0; i < 8; ++i) hv[i] = ld_dev_u32(hsrc + goff + i);
            #pragma unroll
            for (int i = 0; i < 8; ++i) cv[i] = ld_dev_u32(csrc + goff + i);
            unsigned* hls = (unsigned*)h_sb + srow * 260 + scp;
            unsigned* cls = (unsigned*)c_sb + srow * 260 + scp;
            #pragma unroll
            for (int i = 0; i < 8; ++i) hls[i] = hv[i];
            #pragma unroll
            for (int i = 0; i < 8; ++i) cls[i] = cv[i];
        }
        __syncthreads();

        // ---- MFMA: 6 gate k-steps + 2 d k-steps, B in registers ----
        f32x4 accg = {0.f, 0.f, 0.f, 0.f}, accd = {0.f, 0.f, 0.f, 0.f};
        #pragma unroll
        for (int i = 0; i < 6; ++i) {
            const int kk = kbase + i;
            const unsigned short* asrc = (kk < 16)
                ? (h_sb + nn * 520 + kk * 32 + q * 8)
                : (x_sb + nn * 264 + (kk - 16) * 32 + q * 8);
            bf16x8 av = *(const bf16x8*)asrc;
            accg = __builtin_amdgcn_mfma_f32_16x16x32_bf16(av, bw[i], accg, 0, 0, 0);
        }
        #pragma unroll
        for (int i = 0; i < 2; ++i) {
            const int kd = w * 2 + i;
            bf16x8 av = *(const bf16x8*)(c_sb + nn * 520 + kd * 32 + q * 8);
            accd = __builtin_amdgcn_mfma_f32_16x16x32_bf16(av, bd[i], accd, 0, 0, 0);
        }

        // ---- spill partials to LDS (D layout: m = q*4+r, n = nn) ----
        #pragma unroll
        for (int r = 0; r < 4; ++r) {
            Cred[tile][w & 3][(q * 4 + r) * 16 + nn] = accg[r];
            Dred[w][(q * 4 + r) * 16 + nn] = accd[r];
        }
        __syncthreads();

        // ---- reduce + biases + activations ----
        {
            const int tl = t >> 8, pos = t & 255;
            float sv = Cred[tl][0][pos] + Cred[tl][1][pos]
                     + Cred[tl][2][pos] + Cred[tl][3][pos];
            const int m = pos >> 4, n = pos & 15;
            const int g = tl * 2 + (n >> 3), jj = n & 7, jc = j0 + jj;
            sv += Wall_b[g * Hdim + jc] + Uall_b[g * Hdim + jc];
            act[g * 128 + m * 8 + jj] =
                (g == 3) ? tanhf(sv) : 1.0f / (1.0f + expf(-sv));
        }
        if (t < 256) {
            const int m = t >> 4, n = t & 15;
            if (n < 8) {
                float sv = 0.0f;
                #pragma unroll
                for (int ww = 0; ww < 8; ++ww) sv += Dred[ww][t];
                cs1v[m * 8 + n] = tanhf(sv + Wd_b[j0 + n]);
            }
        }
        if (t < 16)
            decv[t] = 1.0f / logf(2.7182818284590452f + ts[(b0 + t) * Sdim + s]);
        __syncthreads();

        // ---- finale: 64 threads, 2 cols each (dword-packed mirror stores) ----
        if (t < 64) {
            const int bl = t >> 2, jl2 = (t & 3) * 2;
            const float dec = decv[bl];
            float hnv[2], cnv[2];
            #pragma unroll
            for (int e = 0; e < 2; ++e) {
                const int u = bl * 8 + jl2 + e;
                const float cs1  = cs1v[u];
                const float cp   = c_own[u];
                const float cadj = (cp - cs1) + cs1 * dec;
                const float f  = act[0 * 128 + u];
                const float ii = act[1 * 128 + u];
                const float oo = act[2 * 128 + u];
                const float gg = act[3 * 128 + u];
                const float cn = f * cadj + ii * gg;
                const float hn = oo * tanhf(cn);
                c_own[u] = cn; hnv[e] = hn; cnv[e] = cn;
                out[((size_t)(b0 + bl) * Sdim + s) * Hdim + j0 + jl2 + e] = hn;
            }
            unsigned* hmw = (unsigned*)(ws + WS_HMIR0 + ((s + 1) & 1) * 65536);
            unsigned* cmw = (unsigned*)(ws + WS_CMIR0 + ((s + 1) & 1) * 65536);
            const int didx = ((b0 + bl) * Hdim + j0 + jl2) >> 1;
            st_dev_u32(hmw + didx, pack2(hnv[0], hnv[1]));
            st_dev_u32(cmw + didx, pack2(cnv[0], cnv[1]));
            if (s == Sdim - 1) {
                float* hf = out + (size_t)Bdim * Sdim * Hdim;
                float* cf = hf + (size_t)Bdim * Hdim;
                #pragma unroll
                for (int e = 0; e < 2; ++e) {
                    hf[(b0 + bl) * Hdim + j0 + jl2 + e] = hnv[e];
                    cf[(b0 + bl) * Hdim + j0 + jl2 + e] = cnv[e];
                }
            }
        }

        if (s == Sdim - 1) break;

        __syncthreads();   // drains each wave's vmcnt -> mirror stores visible
        if (t == 0)
            __hip_atomic_store(&flags[blockIdx.x * FSTR], s + 1,
                               __ATOMIC_RELAXED, __HIP_MEMORY_SCOPE_AGENT);
        stage_x(s + 1);    // overlap with other WGs finishing
        if (t < 64) {      // 64-WG barrier within this bg group only
            while (__hip_atomic_load(&flags[(bg * 64 + t) * FSTR],
                                     __ATOMIC_RELAXED,
                                     __HIP_MEMORY_SCOPE_AGENT) < s + 1) {
                __builtin_amdgcn_s_sleep(1);
            }
        }
        __syncthreads();
    }
}

extern "C" void kernel_launch(void* const* d_in, const int* in_sizes, int n_in,
                              void* d_out, int out_size, void* d_ws, size_t ws_size,
                              hipStream_t stream) {
    const float* x      = (const float*)d_in[0];
    const float* ts     = (const float*)d_in[1];
    const float* Wall   = (const float*)d_in[2];
    const float* Wall_b = (const float*)d_in[3];
    const float* Uall   = (const float*)d_in[4];
    const float* Uall_b = (const float*)d_in[5];
    const float* Wd     = (const float*)d_in[6];
    const float* Wd_b   = (const float*)d_in[7];

    tlstm_prep<<<256, 256, 0, stream>>>(Wall, Uall, Wd, (unsigned char*)d_ws);
    tlstm_mfma<<<NWG, NT, 0, stream>>>(x, ts, Wall_b, Uall_b, Wd_b,
                                       (float*)d_out, (unsigned char*)d_ws);
}